// Round 7
// baseline (171.998 us; speedup 1.0000x reference)
//
#include <hip/hip_runtime.h>

typedef float f32x4 __attribute__((ext_vector_type(4)));
typedef short s16x8 __attribute__((ext_vector_type(8)));

#define QSTEP 25.5f
#define DZ (85.0f/512.0f)

// round-to-nearest-even fp32 -> bf16 (low 16 bits)
__device__ __forceinline__ unsigned rne_bf16(float x) {
  unsigned u = __float_as_uint(x);
  return (u + 0x7FFFu + ((u >> 16) & 1u)) >> 16;
}

// PERSISTENT waves at FULL occupancy: 8192 waves (2048 blocks x 4), each
// loops over tiles { wgid + it*8192 } with 1-deep register prefetch.
// R6 diagnostic showed VGPR=56 / LDS=18.9KB: the kernel fits 8 blocks/CU
// (32 waves/CU) -- launch_bounds(256,8) doubles occupancy vs prior rounds.
// The exposed ~10.3us/pass compute chain (R6: d(dur)/d(nrep)) is dependency-
// stall dominated; 2x TLP hides it behind co-resident waves.
// Verified 16x16x32 bf16 MFMA layouts:
//   A[m=lane&15 (+16*mi)][k=quad*8+j] ; B[k=quad*8+j][n=lane&15 (+16*nj)]
//   D[row=quad*4+r (+16*mi)][col=lane&15 (+16*nj)]
// Chain per tile (coeff = C@X@C^T ; W = quant(coeff) ; rec = (C@W@C)/1023):
//   S1:  tmp   = C @ X        A=C(hi,lo) static, B=X from prefetched regs (hi,lo)
//   S2:  coeff = tmp @ C^T    A=tmp (packed-split LDS plane), B=C^T == C-row frags
//   S3:  U^T   = W^T @ C^T    A=W^T (bf16 plane, b128), B=C^T == C-row frags
//   S4:  rec   = U @ C        A=U   (bf16 plane, b128), B=C == C-col frags
// Dequant LUT (exact in f32): Dq[i] = Q*(i + cs[i]/1024).
__global__ __launch_bounds__(256, 8) void vvc_mfma2_kernel(
    const float* __restrict__ resid,
    const float* __restrict__ dct,
    const float* __restrict__ cshift,
    float* __restrict__ out,
    int niter)
{
  __shared__ float shm[64 + 4 * 1152];   // Dq(64) + per-wave 1152-f32 buffer
  float* Dq   = shm;
  float* Pall = shm + 64;

  const int tid  = threadIdx.x;
  const int wave = tid >> 6;
  const int lane = tid & 63;
  const int col  = lane & 15;
  const int quad = lane >> 4;
  const int k0   = quad * 8;

  // ---- init: C hi/lo planes + C^T hi plane (u16, stride 40 => 16B-aligned rows)
  unsigned short* Chi  = (unsigned short*)Pall;        // [32][40]
  unsigned short* Clo  = Chi + 1280;
  unsigned short* CThi = Chi + 2560;
  {
    float4 cv = ((const float4*)dct)[tid];
    int k = tid >> 3, h = (tid & 7) * 4;
    float vals[4] = {cv.x, cv.y, cv.z, cv.w};
#pragma unroll
    for (int i = 0; i < 4; ++i) {
      unsigned hi = rne_bf16(vals[i]);
      float r = vals[i] - __uint_as_float(hi << 16);
      unsigned lo = rne_bf16(r);
      Chi[k * 40 + h + i]        = (unsigned short)hi;
      Clo[k * 40 + h + i]        = (unsigned short)lo;
      CThi[(h + i) * 40 + k]     = (unsigned short)hi;
    }
    if (tid < 64)
      Dq[tid] = QSTEP * ((float)tid + cshift[tid] * (1.0f / 1024.0f));
  }
  __syncthreads();

  // ---- static fragments (24 VGPRs)
  s16x8 aChi[2], aClo[2], bCThi[2];
#pragma unroll
  for (int i = 0; i < 2; ++i) {
    aChi[i]  = *(const s16x8*)(Chi  + (16 * i + col) * 40 + k0);
    aClo[i]  = *(const s16x8*)(Clo  + (16 * i + col) * 40 + k0);
    bCThi[i] = *(const s16x8*)(CThi + (16 * i + col) * 40 + k0);
  }
  __syncthreads();   // C planes dead; region becomes per-wave buffers

  float* Pw = Pall + wave * 1152;
  const int wgid = blockIdx.x * 4 + wave;          // 0..8191
  const int xoff = k0 * 32 + col;                  // + j*32 + nj*16
  const float* gx = resid + (size_t)wgid * 1024 + xoff;
  float* gout     = out   + (size_t)wgid * 1024;
  const size_t tstride = (size_t)8192 * 1024;      // tile stride per iteration

  // ---- preload tile 0 raw (16 outstanding dword loads)
  float rawA[2][8], rawB[2][8];
#pragma unroll
  for (int nj = 0; nj < 2; ++nj)
#pragma unroll
    for (int j = 0; j < 8; ++j)
      rawA[nj][j] = gx[j * 32 + nj * 16];

  for (int it = 0; it < niter; ++it) {
    // ---- prefetch next tile's X (issue-early; consumed next iteration)
    if (it + 1 < niter) {
      const float* gn = gx + (size_t)(it + 1) * tstride;
#pragma unroll
      for (int nj = 0; nj < 2; ++nj)
#pragma unroll
        for (int j = 0; j < 8; ++j)
          rawB[nj][j] = gn[j * 32 + nj * 16];
    }

    // ---- X -> B-frag hi/lo truncation split (exact)
    s16x8 bXhi[2], bXlo[2];
#pragma unroll
    for (int nj = 0; nj < 2; ++nj)
#pragma unroll
      for (int j = 0; j < 8; ++j) {
        float x = rawA[nj][j] * 1023.0f;
        unsigned u = __float_as_uint(x);
        float r = x - __uint_as_float(u & 0xFFFF0000u);
        bXhi[nj][j] = (short)(u >> 16);
        bXlo[nj][j] = (short)(__float_as_uint(r) >> 16);
      }

    f32x4 acc[2][2];

    // ---- S1: tmp = C @ X  (3-product split)
#pragma unroll
    for (int mi = 0; mi < 2; ++mi)
#pragma unroll
      for (int nj = 0; nj < 2; ++nj) acc[mi][nj] = (f32x4)0.0f;
#pragma unroll
    for (int mi = 0; mi < 2; ++mi)
#pragma unroll
      for (int nj = 0; nj < 2; ++nj) {
        acc[mi][nj] = __builtin_amdgcn_mfma_f32_16x16x32_bf16(aChi[mi], bXhi[nj], acc[mi][nj], 0, 0, 0);
        acc[mi][nj] = __builtin_amdgcn_mfma_f32_16x16x32_bf16(aClo[mi], bXhi[nj], acc[mi][nj], 0, 0, 0);
        acc[mi][nj] = __builtin_amdgcn_mfma_f32_16x16x32_bf16(aChi[mi], bXlo[nj], acc[mi][nj], 0, 0, 0);
      }

    // ---- tmp packed-split plane T[k][w], f32 stride 36 (16B-aligned rows)
    unsigned* T = (unsigned*)Pw;
#pragma unroll
    for (int mi = 0; mi < 2; ++mi)
#pragma unroll
      for (int nj = 0; nj < 2; ++nj)
#pragma unroll
        for (int r = 0; r < 4; ++r) {
          float v = acc[mi][nj][r];
          unsigned u = __float_as_uint(v);
          float rr = v - __uint_as_float(u & 0xFFFF0000u);
          T[(16 * mi + 4 * quad + r) * 36 + 16 * nj + col] =
              (u >> 16) | (__float_as_uint(rr) & 0xFFFF0000u);
        }

    // ---- S2: coeff = tmp @ C^T  (A=tmp split, B=C^T via aChi/aClo)
    s16x8 tHi[2], tLo[2];
#pragma unroll
    for (int mi = 0; mi < 2; ++mi) {
      const unsigned* row = T + (16 * mi + col) * 36 + k0;
      uint4 u0 = *(const uint4*)row, u1 = *(const uint4*)(row + 4);
      s16x8 h, l;
      h[0]=(short)u0.x; h[1]=(short)u0.y; h[2]=(short)u0.z; h[3]=(short)u0.w;
      h[4]=(short)u1.x; h[5]=(short)u1.y; h[6]=(short)u1.z; h[7]=(short)u1.w;
      l[0]=(short)(u0.x>>16); l[1]=(short)(u0.y>>16); l[2]=(short)(u0.z>>16); l[3]=(short)(u0.w>>16);
      l[4]=(short)(u1.x>>16); l[5]=(short)(u1.y>>16); l[6]=(short)(u1.z>>16); l[7]=(short)(u1.w>>16);
      tHi[mi] = h; tLo[mi] = l;
    }
#pragma unroll
    for (int mi = 0; mi < 2; ++mi)
#pragma unroll
      for (int nj = 0; nj < 2; ++nj) acc[mi][nj] = (f32x4)0.0f;
#pragma unroll
    for (int mi = 0; mi < 2; ++mi)
#pragma unroll
      for (int nj = 0; nj < 2; ++nj) {
        acc[mi][nj] = __builtin_amdgcn_mfma_f32_16x16x32_bf16(tHi[mi], aChi[nj], acc[mi][nj], 0, 0, 0);
        acc[mi][nj] = __builtin_amdgcn_mfma_f32_16x16x32_bf16(tLo[mi], aChi[nj], acc[mi][nj], 0, 0, 0);
        acc[mi][nj] = __builtin_amdgcn_mfma_f32_16x16x32_bf16(tHi[mi], aClo[nj], acc[mi][nj], 0, 0, 0);
      }

    // ---- quant + dequant (LUT); write W^T[l][k] bf16 plane (u16 stride 40)
    unsigned short* WT = (unsigned short*)Pw;
#pragma unroll
    for (int mi = 0; mi < 2; ++mi)
#pragma unroll
      for (int nj = 0; nj < 2; ++nj) {
        unsigned w16[4];
#pragma unroll
        for (int r = 0; r < 4; ++r) {
          float cc  = acc[mi][nj][r];
          float qa  = floorf(fabsf(cc) * (1.0f / QSTEP) + DZ);
          int   qi  = (int)qa; qi = qi > 63 ? 63 : qi;
          float lut = Dq[qi];                       // = Q*(qa + cs/1024), exact
          float cah = (qa < 64.0f) ? lut : qa * QSTEP;
          float wv  = (cc < 0.0f) ? -cah : cah;
          w16[r] = rne_bf16(wv);
        }
        uint2 pk; pk.x = w16[0] | (w16[1] << 16); pk.y = w16[2] | (w16[3] << 16);
        *(uint2*)(WT + (16 * nj + col) * 40 + 16 * mi + 4 * quad) = pk;
      }

    // ---- S3: U^T = W^T @ C^T  (A=W^T rows b128, B=C^T via aChi)
    s16x8 wA[2];
#pragma unroll
    for (int mi = 0; mi < 2; ++mi)
      wA[mi] = *(const s16x8*)(WT + (16 * mi + col) * 40 + k0);
#pragma unroll
    for (int mi = 0; mi < 2; ++mi)
#pragma unroll
      for (int nj = 0; nj < 2; ++nj) acc[mi][nj] = (f32x4)0.0f;
#pragma unroll
    for (int mi = 0; mi < 2; ++mi)
#pragma unroll
      for (int nj = 0; nj < 2; ++nj)
        acc[mi][nj] = __builtin_amdgcn_mfma_f32_16x16x32_bf16(wA[mi], aChi[nj], acc[mi][nj], 0, 0, 0);

    // D = U^T[w][h] -> store U[h][w] plane ([D-col][D-row]): b64-packed over r
    unsigned short* U = WT;   // overlay (WT dead after wA loads)
#pragma unroll
    for (int mi = 0; mi < 2; ++mi)
#pragma unroll
      for (int nj = 0; nj < 2; ++nj) {
        unsigned u16v[4];
#pragma unroll
        for (int r = 0; r < 4; ++r) u16v[r] = rne_bf16(acc[mi][nj][r]);
        uint2 pk; pk.x = u16v[0] | (u16v[1] << 16); pk.y = u16v[2] | (u16v[3] << 16);
        *(uint2*)(U + (16 * nj + col) * 40 + 16 * mi + 4 * quad) = pk;
      }

    // ---- S4: rec = U @ C  (A=U rows b128, B=C via bCThi)
    s16x8 uA[2];
#pragma unroll
    for (int mi = 0; mi < 2; ++mi)
      uA[mi] = *(const s16x8*)(U + (16 * mi + col) * 40 + k0);
#pragma unroll
    for (int mi = 0; mi < 2; ++mi)
#pragma unroll
      for (int nj = 0; nj < 2; ++nj) acc[mi][nj] = (f32x4)0.0f;
#pragma unroll
    for (int mi = 0; mi < 2; ++mi)
#pragma unroll
      for (int nj = 0; nj < 2; ++nj)
        acc[mi][nj] = __builtin_amdgcn_mfma_f32_16x16x32_bf16(uA[mi], bCThi[nj], acc[mi][nj], 0, 0, 0);

    // ---- epilogue: /1023, direct D-layout stores (64B segments per instr)
    float* go = gout + (size_t)it * tstride;
#pragma unroll
    for (int mi = 0; mi < 2; ++mi)
#pragma unroll
      for (int nj = 0; nj < 2; ++nj)
#pragma unroll
        for (int r = 0; r < 4; ++r)
          go[(16 * mi + 4 * quad + r) * 32 + 16 * nj + col] =
              acc[mi][nj][r] * (1.0f / 1023.0f);

    // ---- rotate prefetch buffer (vmcnt wait lands here, after compute)
#pragma unroll
    for (int nj = 0; nj < 2; ++nj)
#pragma unroll
      for (int j = 0; j < 8; ++j)
        rawA[nj][j] = rawB[nj][j];
  }
}

extern "C" void kernel_launch(void* const* d_in, const int* in_sizes, int n_in,
                              void* d_out, int out_size, void* d_ws, size_t ws_size,
                              hipStream_t stream) {
  const float* resid  = (const float*)d_in[0];   // [256,64,32,32]
  const float* dct    = (const float*)d_in[1];   // [32,32]
  const float* cshift = (const float*)d_in[2];   // [64]
  float* out = (float*)d_out;

  int tiles  = out_size / 1024;   // 16384
  int blocks = 2048;              // persistent: 8192 waves = 8 blocks/CU (32 waves/CU)
  int niter  = tiles / 8192;      // 2 tiles per wave
  vvc_mfma2_kernel<<<blocks, 256, 0, stream>>>(resid, dct, cshift, out, niter);
}

// Round 8
// 117.001 us; speedup vs baseline: 1.4701x; 1.4701x over previous
//
#include <hip/hip_runtime.h>

typedef float f32x4 __attribute__((ext_vector_type(4)));
typedef short s16x8 __attribute__((ext_vector_type(8)));

#define QSTEP 25.5f
#define DZ (85.0f/512.0f)

// round-to-nearest-even fp32 -> bf16 (low 16 bits)
__device__ __forceinline__ unsigned rne_bf16(float x) {
  unsigned u = __float_as_uint(x);
  return (u + 0x7FFFu + ((u >> 16) & 1u)) >> 16;
}

// One wave per 32x32 tile, launch_bounds(256,6):
//   R6 showed the chain needs ~56 regs; R7 showed 8 waves/EU (64-reg cap)
//   spills catastrophically (WRITE 172MB, VGPR=32). 6 waves/EU = 85-reg cap
//   fits with margin -> 24 waves/CU (1.5x the (256,4) baseline) with zero
//   scratch. LDS 18.9KB/block allows 8 blocks/CU, not the limiter.
// Verified 16x16x32 bf16 MFMA layouts:
//   A[m=lane&15 (+16*mi)][k=quad*8+j] ; B[k=quad*8+j][n=lane&15 (+16*nj)]
//   D[row=quad*4+r (+16*mi)][col=lane&15 (+16*nj)]
// Chain (coeff = C@X@C^T ; W = quant(coeff) ; rec = (C@W@C)/1023):
//   S1:  tmp   = C @ X        A=C(hi,lo) static, B=X from GLOBAL frag loads (hi,lo)
//   S2:  coeff = tmp @ C^T    A=tmp (packed-split LDS plane), B=C^T == C-row frags
//   S3:  U^T   = W^T @ C^T    A=W^T (bf16 plane, b128), B=C^T == C-row frags
//   S4:  rec   = U @ C        A=U   (bf16 plane, b128), B=C == C-col frags
// Dequant LUT (exact in f32): Dq[i] = Q*(i + cs[i]/1024).
__global__ __launch_bounds__(256, 6) void vvc_mfma2_kernel(
    const float* __restrict__ resid,
    const float* __restrict__ dct,
    const float* __restrict__ cshift,
    float* __restrict__ out)
{
  __shared__ float shm[64 + 4 * 1152];   // Dq(64) + per-wave 1152-f32 buffer
  float* Dq   = shm;
  float* Pall = shm + 64;

  const int tid  = threadIdx.x;
  const int wave = tid >> 6;
  const int lane = tid & 63;
  const int col  = lane & 15;
  const int quad = lane >> 4;
  const int k0   = quad * 8;

  // ---- init: C hi/lo planes + C^T hi plane (u16, stride 40 => 16B-aligned rows)
  unsigned short* Chi  = (unsigned short*)Pall;        // [32][40]
  unsigned short* Clo  = Chi + 1280;
  unsigned short* CThi = Chi + 2560;
  {
    float4 cv = ((const float4*)dct)[tid];
    int k = tid >> 3, h = (tid & 7) * 4;
    float vals[4] = {cv.x, cv.y, cv.z, cv.w};
#pragma unroll
    for (int i = 0; i < 4; ++i) {
      unsigned hi = rne_bf16(vals[i]);
      float r = vals[i] - __uint_as_float(hi << 16);
      unsigned lo = rne_bf16(r);
      Chi[k * 40 + h + i]        = (unsigned short)hi;
      Clo[k * 40 + h + i]        = (unsigned short)lo;
      CThi[(h + i) * 40 + k]     = (unsigned short)hi;
    }
    if (tid < 64)
      Dq[tid] = QSTEP * ((float)tid + cshift[tid] * (1.0f / 1024.0f));
  }
  __syncthreads();

  // ---- static fragments (24 VGPRs)
  s16x8 aChi[2], aClo[2], bCThi[2];
#pragma unroll
  for (int i = 0; i < 2; ++i) {
    aChi[i]  = *(const s16x8*)(Chi  + (16 * i + col) * 40 + k0);
    aClo[i]  = *(const s16x8*)(Clo  + (16 * i + col) * 40 + k0);
    bCThi[i] = *(const s16x8*)(CThi + (16 * i + col) * 40 + k0);
  }
  __syncthreads();   // C planes dead; region becomes per-wave buffers

  float* Pw = Pall + wave * 1152;
  const int tile = blockIdx.x * 4 + wave;
  const float* gx = resid + (size_t)tile * 1024;
  float* gout     = out   + (size_t)tile * 1024;

  // ---- X directly from global in B-frag layout; truncation split (no LDS)
  s16x8 bXhi[2], bXlo[2];
#pragma unroll
  for (int nj = 0; nj < 2; ++nj) {
#pragma unroll
    for (int j = 0; j < 8; ++j) {
      float x = gx[(k0 + j) * 32 + nj * 16 + col] * 1023.0f;
      unsigned u  = __float_as_uint(x);
      float r = x - __uint_as_float(u & 0xFFFF0000u);   // exact residual
      bXhi[nj][j] = (short)(u >> 16);
      bXlo[nj][j] = (short)(__float_as_uint(r) >> 16);
    }
  }

  f32x4 acc[2][2];

  // ---- S1: tmp = C @ X  (3-product split)
#pragma unroll
  for (int mi = 0; mi < 2; ++mi)
#pragma unroll
    for (int nj = 0; nj < 2; ++nj) acc[mi][nj] = (f32x4)0.0f;
#pragma unroll
  for (int mi = 0; mi < 2; ++mi)
#pragma unroll
    for (int nj = 0; nj < 2; ++nj) {
      acc[mi][nj] = __builtin_amdgcn_mfma_f32_16x16x32_bf16(aChi[mi], bXhi[nj], acc[mi][nj], 0, 0, 0);
      acc[mi][nj] = __builtin_amdgcn_mfma_f32_16x16x32_bf16(aClo[mi], bXhi[nj], acc[mi][nj], 0, 0, 0);
      acc[mi][nj] = __builtin_amdgcn_mfma_f32_16x16x32_bf16(aChi[mi], bXlo[nj], acc[mi][nj], 0, 0, 0);
    }

  // ---- tmp packed-split plane T[k][w], f32 stride 36 (16B-aligned rows)
  unsigned* T = (unsigned*)Pw;
#pragma unroll
  for (int mi = 0; mi < 2; ++mi)
#pragma unroll
    for (int nj = 0; nj < 2; ++nj)
#pragma unroll
      for (int r = 0; r < 4; ++r) {
        float v = acc[mi][nj][r];
        unsigned u = __float_as_uint(v);
        float rr = v - __uint_as_float(u & 0xFFFF0000u);
        T[(16 * mi + 4 * quad + r) * 36 + 16 * nj + col] =
            (u >> 16) | (__float_as_uint(rr) & 0xFFFF0000u);
      }

  // ---- S2: coeff = tmp @ C^T  (A=tmp split, B=C^T via aChi/aClo)
  s16x8 tHi[2], tLo[2];
#pragma unroll
  for (int mi = 0; mi < 2; ++mi) {
    const unsigned* row = T + (16 * mi + col) * 36 + k0;
    uint4 u0 = *(const uint4*)row, u1 = *(const uint4*)(row + 4);
    s16x8 h, l;
    h[0]=(short)u0.x; h[1]=(short)u0.y; h[2]=(short)u0.z; h[3]=(short)u0.w;
    h[4]=(short)u1.x; h[5]=(short)u1.y; h[6]=(short)u1.z; h[7]=(short)u1.w;
    l[0]=(short)(u0.x>>16); l[1]=(short)(u0.y>>16); l[2]=(short)(u0.z>>16); l[3]=(short)(u0.w>>16);
    l[4]=(short)(u1.x>>16); l[5]=(short)(u1.y>>16); l[6]=(short)(u1.z>>16); l[7]=(short)(u1.w>>16);
    tHi[mi] = h; tLo[mi] = l;
  }
#pragma unroll
  for (int mi = 0; mi < 2; ++mi)
#pragma unroll
    for (int nj = 0; nj < 2; ++nj) acc[mi][nj] = (f32x4)0.0f;
#pragma unroll
  for (int mi = 0; mi < 2; ++mi)
#pragma unroll
    for (int nj = 0; nj < 2; ++nj) {
      acc[mi][nj] = __builtin_amdgcn_mfma_f32_16x16x32_bf16(tHi[mi], aChi[nj], acc[mi][nj], 0, 0, 0);
      acc[mi][nj] = __builtin_amdgcn_mfma_f32_16x16x32_bf16(tLo[mi], aChi[nj], acc[mi][nj], 0, 0, 0);
      acc[mi][nj] = __builtin_amdgcn_mfma_f32_16x16x32_bf16(tHi[mi], aClo[nj], acc[mi][nj], 0, 0, 0);
    }

  // ---- quant + dequant (LUT); write W^T[l][k] bf16 plane (u16 stride 40)
  unsigned short* WT = (unsigned short*)Pw;
#pragma unroll
  for (int mi = 0; mi < 2; ++mi)
#pragma unroll
    for (int nj = 0; nj < 2; ++nj) {
      unsigned w16[4];
#pragma unroll
      for (int r = 0; r < 4; ++r) {
        float cc  = acc[mi][nj][r];
        float qa  = floorf(fabsf(cc) * (1.0f / QSTEP) + DZ);
        int   qi  = (int)qa; qi = qi > 63 ? 63 : qi;
        float lut = Dq[qi];                       // = Q*(qa + cs/1024), exact
        float cah = (qa < 64.0f) ? lut : qa * QSTEP;
        float wv  = (cc < 0.0f) ? -cah : cah;
        w16[r] = rne_bf16(wv);
      }
      uint2 pk; pk.x = w16[0] | (w16[1] << 16); pk.y = w16[2] | (w16[3] << 16);
      *(uint2*)(WT + (16 * nj + col) * 40 + 16 * mi + 4 * quad) = pk;
    }

  // ---- S3: U^T = W^T @ C^T  (A=W^T rows b128, B=C^T via aChi)
  s16x8 wA[2];
#pragma unroll
  for (int mi = 0; mi < 2; ++mi)
    wA[mi] = *(const s16x8*)(WT + (16 * mi + col) * 40 + k0);
#pragma unroll
  for (int mi = 0; mi < 2; ++mi)
#pragma unroll
    for (int nj = 0; nj < 2; ++nj) acc[mi][nj] = (f32x4)0.0f;
#pragma unroll
  for (int mi = 0; mi < 2; ++mi)
#pragma unroll
    for (int nj = 0; nj < 2; ++nj)
      acc[mi][nj] = __builtin_amdgcn_mfma_f32_16x16x32_bf16(wA[mi], aChi[nj], acc[mi][nj], 0, 0, 0);

  // D = U^T[w][h] -> store U[h][w] plane ([D-col][D-row]): b64-packed over r
  unsigned short* U = WT;   // overlay (WT dead after wA loads)
#pragma unroll
  for (int mi = 0; mi < 2; ++mi)
#pragma unroll
    for (int nj = 0; nj < 2; ++nj) {
      unsigned u16v[4];
#pragma unroll
      for (int r = 0; r < 4; ++r) u16v[r] = rne_bf16(acc[mi][nj][r]);
      uint2 pk; pk.x = u16v[0] | (u16v[1] << 16); pk.y = u16v[2] | (u16v[3] << 16);
      *(uint2*)(U + (16 * nj + col) * 40 + 16 * mi + 4 * quad) = pk;
    }

  // ---- S4: rec = U @ C  (A=U rows b128, B=C via bCThi)
  s16x8 uA[2];
#pragma unroll
  for (int mi = 0; mi < 2; ++mi)
    uA[mi] = *(const s16x8*)(U + (16 * mi + col) * 40 + k0);
#pragma unroll
  for (int mi = 0; mi < 2; ++mi)
#pragma unroll
    for (int nj = 0; nj < 2; ++nj) acc[mi][nj] = (f32x4)0.0f;
#pragma unroll
  for (int mi = 0; mi < 2; ++mi)
#pragma unroll
    for (int nj = 0; nj < 2; ++nj)
      acc[mi][nj] = __builtin_amdgcn_mfma_f32_16x16x32_bf16(uA[mi], bCThi[nj], acc[mi][nj], 0, 0, 0);

  // ---- epilogue: /1023, direct D-layout stores (64B segments per instr)
#pragma unroll
  for (int mi = 0; mi < 2; ++mi)
#pragma unroll
    for (int nj = 0; nj < 2; ++nj)
#pragma unroll
      for (int r = 0; r < 4; ++r)
        gout[(16 * mi + 4 * quad + r) * 32 + 16 * nj + col] =
            acc[mi][nj][r] * (1.0f / 1023.0f);
}

extern "C" void kernel_launch(void* const* d_in, const int* in_sizes, int n_in,
                              void* d_out, int out_size, void* d_ws, size_t ws_size,
                              hipStream_t stream) {
  const float* resid  = (const float*)d_in[0];   // [256,64,32,32]
  const float* dct    = (const float*)d_in[1];   // [32,32]
  const float* cshift = (const float*)d_in[2];   // [64]
  float* out = (float*)d_out;

  int tiles  = out_size / 1024;   // 16384
  int blocks = tiles / 4;         // 1 tile per wave, 4 waves per block
  vvc_mfma2_kernel<<<blocks, 256, 0, stream>>>(resid, dct, cshift, out);
}

// Round 10
// 116.366 us; speedup vs baseline: 1.4781x; 1.0054x over previous
//
#include <hip/hip_runtime.h>
#include <hip/hip_bf16.h>

typedef float f32x4 __attribute__((ext_vector_type(4)));
typedef short s16x8 __attribute__((ext_vector_type(8)));

#define QSTEP 25.5f
#define DZ (85.0f/512.0f)

// round-to-nearest-even fp32 -> bf16 (low 16 bits) -- used in prologue only
__device__ __forceinline__ unsigned rne_bf16(float x) {
  unsigned u = __float_as_uint(x);
  return (u + 0x7FFFu + ((u >> 16) & 1u)) >> 16;
}

// packed RNE f32x2 -> bf16x2 via header intrinsic (compiler-lowered; RNE is
// bit-identical to rne_bf16 for finite values). NO inline asm (R9 lesson).
__device__ __forceinline__ unsigned pack2_bf16(float lo, float hi) {
  union { __hip_bfloat162 h; unsigned u; } cv;
  cv.h = __float22bfloat162_rn(make_float2(lo, hi));
  return cv.u;
}

// One wave per 32x32 tile, launch_bounds(256,4) (R8: (256,6) neutral).
// Model (R6/R7 counters): kernel ~34us = HBM-ceiling memory phase (~16-20us,
// FETCH 33MB L3-assisted + WRITE 65MB) + VALU-issue-bound compute (~8.3us/SIMD
// demand; R6 slope 10.3us/pass) + stalls. Only instruction removal moves dur.
// This round: safe VALU diet (integer quant, header bf16 cvt, split T planes).
// Verified 16x16x32 bf16 MFMA layouts:
//   A[m=lane&15 (+16*mi)][k=quad*8+j] ; B[k=quad*8+j][n=lane&15 (+16*nj)]
//   D[row=quad*4+r (+16*mi)][col=lane&15 (+16*nj)]
// Chain (coeff = C@X@C^T ; W = quant(coeff) ; rec = (C@W@C)/1023):
//   S1:  tmp   = C @ X        A=C(hi,lo) static, B=X from GLOBAL frag loads (hi,lo)
//   S2:  coeff = tmp @ C^T    A=tmp (Thi/Tlo u16 planes, b128 direct frags), B=C^T
//   S3:  U^T   = W^T @ C^T    A=W^T (bf16 plane, b128), B=C^T == C-row frags
//   S4:  rec   = U @ C        A=U   (bf16 plane, b128), B=C == C-col frags
// Dequant LUT (exact in f32): Dq[i] = Q*(i + cs[i]/1024).
__global__ __launch_bounds__(256, 4) void vvc_mfma2_kernel(
    const float* __restrict__ resid,
    const float* __restrict__ dct,
    const float* __restrict__ cshift,
    float* __restrict__ out)
{
  __shared__ float shm[64 + 4 * 1280];   // Dq(64) + per-wave 1280-f32 buffer
  float* Dq   = shm;
  float* Pall = shm + 64;

  const int tid  = threadIdx.x;
  const int wave = tid >> 6;
  const int lane = tid & 63;
  const int col  = lane & 15;
  const int quad = lane >> 4;
  const int k0   = quad * 8;

  // ---- init: C hi/lo planes + C^T hi plane (u16, stride 40 => 16B-aligned rows)
  unsigned short* Chi  = (unsigned short*)Pall;        // [32][40]
  unsigned short* Clo  = Chi + 1280;
  unsigned short* CThi = Chi + 2560;
  {
    float4 cv = ((const float4*)dct)[tid];
    int k = tid >> 3, h = (tid & 7) * 4;
    float vals[4] = {cv.x, cv.y, cv.z, cv.w};
#pragma unroll
    for (int i = 0; i < 4; ++i) {
      unsigned hi = rne_bf16(vals[i]);
      float r = vals[i] - __uint_as_float(hi << 16);
      unsigned lo = rne_bf16(r);
      Chi[k * 40 + h + i]        = (unsigned short)hi;
      Clo[k * 40 + h + i]        = (unsigned short)lo;
      CThi[(h + i) * 40 + k]     = (unsigned short)hi;
    }
    if (tid < 64)
      Dq[tid] = QSTEP * ((float)tid + cshift[tid] * (1.0f / 1024.0f));
  }
  __syncthreads();

  // ---- static fragments (24 VGPRs)
  s16x8 aChi[2], aClo[2], bCThi[2];
#pragma unroll
  for (int i = 0; i < 2; ++i) {
    aChi[i]  = *(const s16x8*)(Chi  + (16 * i + col) * 40 + k0);
    aClo[i]  = *(const s16x8*)(Clo  + (16 * i + col) * 40 + k0);
    bCThi[i] = *(const s16x8*)(CThi + (16 * i + col) * 40 + k0);
  }
  __syncthreads();   // C planes dead; region becomes per-wave buffers

  float* Pw = Pall + wave * 1280;
  const int tile = blockIdx.x * 4 + wave;
  const float* gx = resid + (size_t)tile * 1024;
  float* gout     = out   + (size_t)tile * 1024;

  // ---- X directly from global in B-frag layout; truncation split (no LDS)
  s16x8 bXhi[2], bXlo[2];
#pragma unroll
  for (int nj = 0; nj < 2; ++nj) {
#pragma unroll
    for (int j = 0; j < 8; ++j) {
      float x = gx[(k0 + j) * 32 + nj * 16 + col] * 1023.0f;
      unsigned u  = __float_as_uint(x);
      float r = x - __uint_as_float(u & 0xFFFF0000u);   // exact residual
      bXhi[nj][j] = (short)(u >> 16);
      bXlo[nj][j] = (short)(__float_as_uint(r) >> 16);
    }
  }

  f32x4 acc[2][2];

  // ---- S1: tmp = C @ X  (3-product split)
#pragma unroll
  for (int mi = 0; mi < 2; ++mi)
#pragma unroll
    for (int nj = 0; nj < 2; ++nj) acc[mi][nj] = (f32x4)0.0f;
#pragma unroll
  for (int mi = 0; mi < 2; ++mi)
#pragma unroll
    for (int nj = 0; nj < 2; ++nj) {
      acc[mi][nj] = __builtin_amdgcn_mfma_f32_16x16x32_bf16(aChi[mi], bXhi[nj], acc[mi][nj], 0, 0, 0);
      acc[mi][nj] = __builtin_amdgcn_mfma_f32_16x16x32_bf16(aClo[mi], bXhi[nj], acc[mi][nj], 0, 0, 0);
      acc[mi][nj] = __builtin_amdgcn_mfma_f32_16x16x32_bf16(aChi[mi], bXlo[nj], acc[mi][nj], 0, 0, 0);
    }

  // ---- tmp truncation split into TWO u16 planes Thi/Tlo [32][40]
  //      (b128 reads land directly in s16x8 frags -> no unpack in S2)
  unsigned short* Thi = (unsigned short*)Pw;           // [32][40]
  unsigned short* Tlo = Thi + 1280;
#pragma unroll
  for (int mi = 0; mi < 2; ++mi)
#pragma unroll
    for (int nj = 0; nj < 2; ++nj)
#pragma unroll
      for (int r = 0; r < 4; ++r) {
        float v = acc[mi][nj][r];
        unsigned u = __float_as_uint(v);
        float rr = v - __uint_as_float(u & 0xFFFF0000u);
        int idx = (16 * mi + 4 * quad + r) * 40 + 16 * nj + col;
        Thi[idx] = (unsigned short)(u >> 16);
        Tlo[idx] = (unsigned short)(__float_as_uint(rr) >> 16);
      }

  // ---- S2: coeff = tmp @ C^T  (A=tmp hi/lo frags direct, B=C^T via aChi/aClo)
  s16x8 tHi[2], tLo[2];
#pragma unroll
  for (int mi = 0; mi < 2; ++mi) {
    tHi[mi] = *(const s16x8*)(Thi + (16 * mi + col) * 40 + k0);
    tLo[mi] = *(const s16x8*)(Tlo + (16 * mi + col) * 40 + k0);
  }
#pragma unroll
  for (int mi = 0; mi < 2; ++mi)
#pragma unroll
    for (int nj = 0; nj < 2; ++nj) acc[mi][nj] = (f32x4)0.0f;
#pragma unroll
  for (int mi = 0; mi < 2; ++mi)
#pragma unroll
    for (int nj = 0; nj < 2; ++nj) {
      acc[mi][nj] = __builtin_amdgcn_mfma_f32_16x16x32_bf16(tHi[mi], aChi[nj], acc[mi][nj], 0, 0, 0);
      acc[mi][nj] = __builtin_amdgcn_mfma_f32_16x16x32_bf16(tLo[mi], aChi[nj], acc[mi][nj], 0, 0, 0);
      acc[mi][nj] = __builtin_amdgcn_mfma_f32_16x16x32_bf16(tHi[mi], aClo[nj], acc[mi][nj], 0, 0, 0);
    }

  // ---- quant + dequant (integer form + LUT); write W^T[l][k] bf16 plane
  //      qi=(int)(|cc|/Q+DZ) == floor (arg>0, same mul+add as R8); sign by
  //      bit-or (cah>=0; +-0 corner gives W=+-0 -> identical products).
  unsigned short* WT = (unsigned short*)Pw;
#pragma unroll
  for (int mi = 0; mi < 2; ++mi)
#pragma unroll
    for (int nj = 0; nj < 2; ++nj) {
      float wv[4];
#pragma unroll
      for (int r = 0; r < 4; ++r) {
        float cc  = acc[mi][nj][r];
        float t   = fabsf(cc) * (1.0f / QSTEP) + DZ;
        int   qi  = (int)t;                       // == floor(t), t > 0
        int   qc  = qi > 63 ? 63 : qi;
        float lut = Dq[qc];                       // = Q*(qi + cs/1024), exact
        float cah = (qi < 64) ? lut : (float)qi * QSTEP;
        wv[r] = __uint_as_float(__float_as_uint(cah) |
                                (__float_as_uint(cc) & 0x80000000u));
      }
      uint2 pk; pk.x = pack2_bf16(wv[0], wv[1]); pk.y = pack2_bf16(wv[2], wv[3]);
      *(uint2*)(WT + (16 * nj + col) * 40 + 16 * mi + 4 * quad) = pk;
    }

  // ---- S3: U^T = W^T @ C^T  (A=W^T rows b128, B=C^T via aChi)
  s16x8 wA[2];
#pragma unroll
  for (int mi = 0; mi < 2; ++mi)
    wA[mi] = *(const s16x8*)(WT + (16 * mi + col) * 40 + k0);
#pragma unroll
  for (int mi = 0; mi < 2; ++mi)
#pragma unroll
    for (int nj = 0; nj < 2; ++nj) acc[mi][nj] = (f32x4)0.0f;
#pragma unroll
  for (int mi = 0; mi < 2; ++mi)
#pragma unroll
    for (int nj = 0; nj < 2; ++nj)
      acc[mi][nj] = __builtin_amdgcn_mfma_f32_16x16x32_bf16(wA[mi], aChi[nj], acc[mi][nj], 0, 0, 0);

  // D = U^T[w][h] -> store U[h][w] plane ([D-col][D-row]): b64-packed over r
  unsigned short* U = WT;   // overlay (WT dead after wA loads)
#pragma unroll
  for (int mi = 0; mi < 2; ++mi)
#pragma unroll
    for (int nj = 0; nj < 2; ++nj) {
      uint2 pk;
      pk.x = pack2_bf16(acc[mi][nj][0], acc[mi][nj][1]);
      pk.y = pack2_bf16(acc[mi][nj][2], acc[mi][nj][3]);
      *(uint2*)(U + (16 * nj + col) * 40 + 16 * mi + 4 * quad) = pk;
    }

  // ---- S4: rec = U @ C  (A=U rows b128, B=C via bCThi)
  s16x8 uA[2];
#pragma unroll
  for (int mi = 0; mi < 2; ++mi)
    uA[mi] = *(const s16x8*)(U + (16 * mi + col) * 40 + k0);
#pragma unroll
  for (int mi = 0; mi < 2; ++mi)
#pragma unroll
    for (int nj = 0; nj < 2; ++nj) acc[mi][nj] = (f32x4)0.0f;
#pragma unroll
  for (int mi = 0; mi < 2; ++mi)
#pragma unroll
    for (int nj = 0; nj < 2; ++nj)
      acc[mi][nj] = __builtin_amdgcn_mfma_f32_16x16x32_bf16(uA[mi], bCThi[nj], acc[mi][nj], 0, 0, 0);

  // ---- epilogue: /1023, direct D-layout stores (64B segments per instr)
#pragma unroll
  for (int mi = 0; mi < 2; ++mi)
#pragma unroll
    for (int nj = 0; nj < 2; ++nj)
#pragma unroll
      for (int r = 0; r < 4; ++r)
        gout[(16 * mi + 4 * quad + r) * 32 + 16 * nj + col] =
            acc[mi][nj][r] * (1.0f / 1023.0f);
}

extern "C" void kernel_launch(void* const* d_in, const int* in_sizes, int n_in,
                              void* d_out, int out_size, void* d_ws, size_t ws_size,
                              hipStream_t stream) {
  const float* resid  = (const float*)d_in[0];   // [256,64,32,32]
  const float* dct    = (const float*)d_in[1];   // [32,32]
  const float* cshift = (const float*)d_in[2];   // [64]
  float* out = (float*)d_out;

  int tiles  = out_size / 1024;   // 16384
  int blocks = tiles / 4;         // 1 tile per wave, 4 waves per block
  vvc_mfma2_kernel<<<blocks, 256, 0, stream>>>(resid, dct, cshift, out);
}